// Round 3
// baseline (188.343 us; speedup 1.0000x reference)
//
#include <hip/hip_runtime.h>
#include <hip/hip_bf16.h>
#include <stdint.h>

#define T_TOK 8192
#define DIN   1024
#define DOUT  1024
#define NEXP  8
#define CAP   1024
#define LN_EPS 1e-5f

#define BM 128
#define BN 128
#define BK 32
#define LDSS 48   // fallback kernel only

typedef __attribute__((ext_vector_type(8))) short short8;
typedef __attribute__((ext_vector_type(4))) float f32x4;

__device__ __forceinline__ unsigned short f2bf(float f) {
    union { float f; unsigned int u; } v; v.f = f;
    unsigned int u = v.u;
    unsigned int r = u + 0x7FFFu + ((u >> 16) & 1u);   // RNE
    return (unsigned short)(r >> 16);
}

__device__ __forceinline__ void gld16(void* l, const void* g) {
    __builtin_amdgcn_global_load_lds(
        (const __attribute__((address_space(1))) unsigned int*)(uintptr_t)g,
        (__attribute__((address_space(3))) unsigned int*)(uintptr_t)l,
        16, 0, 0);
}

// ---- prep: [0,8192) X->Xb bf16 | [8192,16384) W->Wt^T bf16 | [16384,16400) zero stats/ctr ----
__global__ __launch_bounds__(256) void prep_kernel(
    const float* __restrict__ X, const float* __restrict__ W,
    unsigned short* __restrict__ Xb, unsigned short* __restrict__ Wt,
    float4* __restrict__ stats4, int* __restrict__ ctr) {
    __shared__ float tile[32][33];
    int blk = blockIdx.x;
    int tid = threadIdx.x;
    if (blk < 8192) {
        int i = blk * 256 + tid;
        float4 v = ((const float4*)X)[i];
        ushort4 o;
        o.x = f2bf(v.x); o.y = f2bf(v.y); o.z = f2bf(v.z); o.w = f2bf(v.w);
        ((ushort4*)Xb)[i] = o;
    } else if (blk < 16384) {
        int t  = blk - 8192;
        int e  = t >> 10;
        int k0 = ((t >> 5) & 31) * 32;
        int n0 = (t & 31) * 32;
        const float* Wp = W + (size_t)e * DIN * DOUT;
        unsigned short* Wtp = Wt + (size_t)e * DIN * DOUT;
        {
            int k  = tid >> 3;
            int c4 = tid & 7;
            float4 v = *(const float4*)(Wp + (size_t)(k0 + k) * DOUT + n0 + c4 * 4);
            tile[k][c4 * 4 + 0] = v.x; tile[k][c4 * 4 + 1] = v.y;
            tile[k][c4 * 4 + 2] = v.z; tile[k][c4 * 4 + 3] = v.w;
        }
        __syncthreads();
        {
            int n  = tid >> 3;
            int kc = tid & 7;
            ushort4 o;
            o.x = f2bf(tile[kc * 4 + 0][n]);
            o.y = f2bf(tile[kc * 4 + 1][n]);
            o.z = f2bf(tile[kc * 4 + 2][n]);
            o.w = f2bf(tile[kc * 4 + 3][n]);
            *(ushort4*)(Wtp + (size_t)(n0 + n) * DIN + k0 + kc * 4) = o;
        }
    } else {
        int z = blk - 16384;                 // 0..15, 4096 float4 of stats
        stats4[z * 256 + tid] = make_float4(0.f, 0.f, 0.f, 0.f);
        if (z == 0 && tid < 64) ctr[tid] = 0;
    }
}

// ---- fused GEMM + bias + relu + LayerNorm ----
// 128x128x32, 4 waves, 4x4 mfma_f32_16x16x32_bf16. e = blk&7 (XCD affinity).
// Epilogue: per-row partial sums -> same-XCD atomics; strip counter; spin;
// normalize register tile; single fp32 write of the final output.
__global__ __launch_bounds__(256, 2) void gemm3_kernel(
    const unsigned short* __restrict__ Xb,   // [T][K] bf16
    const unsigned short* __restrict__ Wt,   // [E][N][K] bf16
    const float* __restrict__ Bias,
    const float* __restrict__ G,
    const float* __restrict__ Bt,
    float* __restrict__ stats,               // [8192][2] (sum, sumsq)
    int* __restrict__ ctr,                   // [64] strip arrival counters
    float* __restrict__ Out)
{
    __shared__ unsigned short As[BM * BK];
    __shared__ unsigned short Bs[BN * BK];

    int blk = blockIdx.x;                    // 0..511
    int e   = blk & 7;
    int mi  = blk >> 6;                      // 0..7
    int m0  = mi * BM;
    int n0  = ((blk >> 3) & 7) * BN;
    int strip = e * 8 + mi;

    int tid  = threadIdx.x;
    int wave = tid >> 6;
    int lane = tid & 63;
    int wm   = (wave >> 1) * 64;
    int wn   = (wave & 1) * 64;
    int lrow = lane & 15;
    int quad = lane >> 4;

    const unsigned short* Ag = Xb + (size_t)(e * CAP + m0) * DIN;
    const unsigned short* Bg = Wt + (size_t)e * DOUT * DIN + (size_t)n0 * DIN;

    int l0 = tid;
    int l1 = tid + 256;
    int ar0 = l0 >> 2, ac0 = (l0 & 3) * 8;
    int ar1 = l1 >> 2, ac1 = (l1 & 3) * 8;

    f32x4 acc[4][4];
#pragma unroll
    for (int i = 0; i < 4; i++)
#pragma unroll
        for (int j = 0; j < 4; j++)
            acc[i][j] = (f32x4)(0.0f);

    for (int k0 = 0; k0 < DIN; k0 += BK) {
        gld16(&As[l0 * 8], Ag + (size_t)ar0 * DIN + k0 + ac0);
        gld16(&As[l1 * 8], Ag + (size_t)ar1 * DIN + k0 + ac1);
        gld16(&Bs[l0 * 8], Bg + (size_t)ar0 * DIN + k0 + ac0);
        gld16(&Bs[l1 * 8], Bg + (size_t)ar1 * DIN + k0 + ac1);
        __syncthreads();

        short8 af[4], bf[4];
#pragma unroll
        for (int i = 0; i < 4; i++)
            af[i] = *(const short8*)&As[(wm + i * 16 + lrow) * BK + quad * 8];
#pragma unroll
        for (int j = 0; j < 4; j++)
            bf[j] = *(const short8*)&Bs[(wn + j * 16 + lrow) * BK + quad * 8];
#pragma unroll
        for (int i = 0; i < 4; i++)
#pragma unroll
            for (int j = 0; j < 4; j++)
                acc[i][j] = __builtin_amdgcn_mfma_f32_16x16x32_bf16(af[i], bf[j], acc[i][j], 0, 0, 0);
        __syncthreads();
    }

    // per-lane col params
    float bias[4], gg[4], bb[4];
#pragma unroll
    for (int j = 0; j < 4; j++) {
        int col = e * DOUT + n0 + wn + j * 16 + lrow;
        bias[j] = Bias[col];
        gg[j]   = G[col];
        bb[j]   = Bt[col];
    }

    int tok0 = e * CAP + m0 + wm;

    // bias + relu (in place) and per-row partial sums over this block's 64 cols
#pragma unroll
    for (int i = 0; i < 4; i++) {
#pragma unroll
        for (int r = 0; r < 4; r++) {
            float s = 0.f, ss = 0.f;
#pragma unroll
            for (int j = 0; j < 4; j++) {
                float v = fmaxf(acc[i][j][r] + bias[j], 0.f);
                acc[i][j][r] = v;
                s += v;
                ss = fmaf(v, v, ss);
            }
#pragma unroll
            for (int m = 1; m <= 8; m <<= 1) {   // reduce across lrow within quad
                s  += __shfl_xor(s, m);
                ss += __shfl_xor(ss, m);
            }
            if (lrow == 0) {
                int grow = tok0 + i * 16 + quad * 4 + r;
                unsafeAtomicAdd(&stats[2 * grow],     s);
                unsafeAtomicAdd(&stats[2 * grow + 1], ss);
            }
        }
    }

    // strip barrier: wait for all 8 n-blocks of this row strip
    __syncthreads();                 // drains vmcnt -> all atomics complete
    if (tid == 0) {
        __threadfence();
        atomicAdd(&ctr[strip], 1);
        while (atomicAdd(&ctr[strip], 0) < 8)
            __builtin_amdgcn_s_sleep(8);
    }
    __syncthreads();
    __threadfence();                 // invalidate L1 before reading stats

    // normalize register tile and write final output
#pragma unroll
    for (int i = 0; i < 4; i++) {
#pragma unroll
        for (int r = 0; r < 4; r++) {
            int grow = tok0 + i * 16 + quad * 4 + r;
            float su = stats[2 * grow];
            float sq = stats[2 * grow + 1];
            float mu  = su * (1.0f / DOUT);
            float var = fmaxf(sq * (1.0f / DOUT) - mu * mu, 0.f);
            float rs  = rsqrtf(var + LN_EPS);
#pragma unroll
            for (int j = 0; j < 4; j++) {
                int gcol = n0 + wn + j * 16 + lrow;
                Out[(size_t)grow * DOUT + gcol] = (acc[i][j][r] - mu) * rs * gg[j] + bb[j];
            }
        }
    }
}

// ================= fallback path (ws too small): R2 kernels =================
__global__ __launch_bounds__(256, 2) void gemm_fb_kernel(
    const float* __restrict__ X, const unsigned short* __restrict__ Wt,
    const float* __restrict__ Bias, float* __restrict__ H)
{
    __shared__ unsigned short As[BM * LDSS];
    __shared__ unsigned short Bs[BN * LDSS];
    int blk = blockIdx.x;
    int e   = blk >> 6;
    int tt  = blk & 63;
    int m0  = (tt >> 3) * BM;
    int n0  = (tt & 7) * BN;
    int tid  = threadIdx.x;
    int wave = tid >> 6;
    int lane = tid & 63;
    int wm   = (wave >> 1) * 64;
    int wn   = (wave & 1) * 64;
    int lrow = lane & 15;
    int quad = lane >> 4;
    const float* Xe = X + (size_t)(e * CAP + m0) * DIN;
    const unsigned short* We = Wt + (size_t)e * DOUT * DIN + (size_t)n0 * DIN;
    f32x4 acc[4][4];
#pragma unroll
    for (int i = 0; i < 4; i++)
#pragma unroll
        for (int j = 0; j < 4; j++)
            acc[i][j] = (f32x4)(0.0f);
    for (int k0 = 0; k0 < DIN; k0 += BK) {
#pragma unroll
        for (int i = 0; i < 4; i++) {
            int idx = tid + i * 256;
            int row = idx >> 3;
            int c4  = idx & 7;
            const float4 xv = *(const float4*)(Xe + (size_t)row * DIN + k0 + c4 * 4);
            ushort4 bv;
            bv.x = f2bf(xv.x); bv.y = f2bf(xv.y); bv.z = f2bf(xv.z); bv.w = f2bf(xv.w);
            *(ushort4*)&As[row * LDSS + c4 * 4] = bv;
        }
#pragma unroll
        for (int i = 0; i < 2; i++) {
            int idx = tid + i * 256;
            int row = idx >> 2;
            int c   = idx & 3;
            uint4 wv = *(const uint4*)(We + (size_t)row * DIN + k0 + c * 8);
            *(uint4*)&Bs[row * LDSS + c * 8] = wv;
        }
        __syncthreads();
        short8 af[4], bf[4];
#pragma unroll
        for (int i = 0; i < 4; i++)
            af[i] = *(const short8*)&As[(wm + i * 16 + lrow) * LDSS + quad * 8];
#pragma unroll
        for (int j = 0; j < 4; j++)
            bf[j] = *(const short8*)&Bs[(wn + j * 16 + lrow) * LDSS + quad * 8];
#pragma unroll
        for (int i = 0; i < 4; i++)
#pragma unroll
            for (int j = 0; j < 4; j++)
                acc[i][j] = __builtin_amdgcn_mfma_f32_16x16x32_bf16(af[i], bf[j], acc[i][j], 0, 0, 0);
        __syncthreads();
    }
    float bias[4];
#pragma unroll
    for (int j = 0; j < 4; j++)
        bias[j] = Bias[e * DOUT + n0 + wn + j * 16 + lrow];
    int tok0 = e * CAP + m0 + wm;
#pragma unroll
    for (int i = 0; i < 4; i++)
#pragma unroll
        for (int j = 0; j < 4; j++) {
            int col = n0 + wn + j * 16 + lrow;
#pragma unroll
            for (int r = 0; r < 4; r++) {
                int row = tok0 + i * 16 + quad * 4 + r;
                float v = acc[i][j][r] + bias[j];
                H[(size_t)row * DOUT + col] = fmaxf(v, 0.0f);
            }
        }
}

__global__ __launch_bounds__(256) void ln_kernel(float* __restrict__ H,
                                                 const float* __restrict__ G,
                                                 const float* __restrict__ Bt) {
    int row = blockIdx.x;
    int e   = row >> 10;
    int tid  = threadIdx.x;
    int wave = tid >> 6;
    int lane = tid & 63;
    float* hp = H + (size_t)row * DOUT;
    float4 x = *(const float4*)(hp + tid * 4);
    float s  = x.x + x.y + x.z + x.w;
    float ss = fmaf(x.x, x.x, fmaf(x.y, x.y, fmaf(x.z, x.z, x.w * x.w)));
#pragma unroll
    for (int m = 32; m >= 1; m >>= 1) {
        s  += __shfl_xor(s, m);
        ss += __shfl_xor(ss, m);
    }
    __shared__ float red[8];
    if (lane == 0) { red[wave] = s; red[4 + wave] = ss; }
    __syncthreads();
    float ts  = red[0] + red[1] + red[2] + red[3];
    float tss = red[4] + red[5] + red[6] + red[7];
    float mean = ts * (1.0f / DOUT);
    float var  = fmaxf(tss * (1.0f / DOUT) - mean * mean, 0.0f);
    float rs = rsqrtf(var + LN_EPS);
    float4 g = *(const float4*)(G  + (size_t)e * DOUT + tid * 4);
    float4 b = *(const float4*)(Bt + (size_t)e * DOUT + tid * 4);
    float4 y;
    y.x = (x.x - mean) * rs * g.x + b.x;
    y.y = (x.y - mean) * rs * g.y + b.y;
    y.z = (x.z - mean) * rs * g.z + b.z;
    y.w = (x.w - mean) * rs * g.w + b.w;
    *(float4*)(hp + tid * 4) = y;
}

__global__ __launch_bounds__(256) void wt_only_kernel(const float* __restrict__ W,
                                                      unsigned short* __restrict__ Wt) {
    __shared__ float tile[32][33];
    int t  = blockIdx.x;
    int e  = t >> 10;
    int k0 = ((t >> 5) & 31) * 32;
    int n0 = (t & 31) * 32;
    int tid = threadIdx.x;
    const float* Wp = W + (size_t)e * DIN * DOUT;
    unsigned short* Wtp = Wt + (size_t)e * DIN * DOUT;
    {
        int k  = tid >> 3;
        int c4 = tid & 7;
        float4 v = *(const float4*)(Wp + (size_t)(k0 + k) * DOUT + n0 + c4 * 4);
        tile[k][c4 * 4 + 0] = v.x; tile[k][c4 * 4 + 1] = v.y;
        tile[k][c4 * 4 + 2] = v.z; tile[k][c4 * 4 + 3] = v.w;
    }
    __syncthreads();
    {
        int n  = tid >> 3;
        int kc = tid & 7;
        ushort4 o;
        o.x = f2bf(tile[kc * 4 + 0][n]);
        o.y = f2bf(tile[kc * 4 + 1][n]);
        o.z = f2bf(tile[kc * 4 + 2][n]);
        o.w = f2bf(tile[kc * 4 + 3][n]);
        *(ushort4*)(Wtp + (size_t)(n0 + n) * DIN + k0 + kc * 4) = o;
    }
}

extern "C" void kernel_launch(void* const* d_in, const int* in_sizes, int n_in,
                              void* d_out, int out_size, void* d_ws, size_t ws_size,
                              hipStream_t stream) {
    const float* x  = (const float*)d_in[0];
    const float* W  = (const float*)d_in[2];
    const float* b  = (const float*)d_in[3];
    const float* g  = (const float*)d_in[4];
    const float* be = (const float*)d_in[5];
    float* out = (float*)d_out;

    const size_t WT_BYTES = (size_t)NEXP * DIN * DOUT * 2;   // 16 MB
    const size_t XB_BYTES = (size_t)T_TOK * DIN * 2;         // 16 MB
    const size_t ST_BYTES = (size_t)T_TOK * 2 * 4;           // 64 KB
    const size_t NEEDED   = WT_BYTES + XB_BYTES + ST_BYTES + 256;

    unsigned short* Wt = (unsigned short*)d_ws;
    dim3 tb(256);

    if (ws_size >= NEEDED) {
        unsigned short* Xb = (unsigned short*)((char*)d_ws + WT_BYTES);
        float* stats = (float*)((char*)d_ws + WT_BYTES + XB_BYTES);
        int* ctr = (int*)((char*)d_ws + WT_BYTES + XB_BYTES + ST_BYTES);
        prep_kernel<<<dim3(16400), tb, 0, stream>>>(x, W, Xb, Wt, (float4*)stats, ctr);
        gemm3_kernel<<<dim3(512), tb, 0, stream>>>(Xb, Wt, b, g, be, stats, ctr, out);
    } else {
        wt_only_kernel<<<dim3(8192), tb, 0, stream>>>(W, Wt);
        gemm_fb_kernel<<<dim3(512), tb, 0, stream>>>(x, Wt, b, out);
        ln_kernel<<<dim3(8192), tb, 0, stream>>>(out, g, be);
    }
}

// Round 4
// 154.915 us; speedup vs baseline: 1.2158x; 1.2158x over previous
//
#include <hip/hip_runtime.h>
#include <hip/hip_bf16.h>
#include <stdint.h>

#define T_TOK 8192
#define DIN   1024
#define DOUT  1024
#define NEXP  8
#define CAP   1024
#define LN_EPS 1e-5f

#define BM 128
#define BN 128
#define BK 32
#define LDSS 48   // fallback kernel only

typedef __attribute__((ext_vector_type(8))) short short8;
typedef __attribute__((ext_vector_type(4))) float f32x4;

__device__ __forceinline__ unsigned short f2bf(float f) {
    union { float f; unsigned int u; } v; v.f = f;
    unsigned int u = v.u;
    unsigned int r = u + 0x7FFFu + ((u >> 16) & 1u);   // RNE
    return (unsigned short)(r >> 16);
}
__device__ __forceinline__ float bf2f(unsigned short h) {
    union { unsigned int u; float f; } v; v.u = ((unsigned int)h) << 16;
    return v.f;
}

__device__ __forceinline__ void gld16(void* l, const void* g) {
    __builtin_amdgcn_global_load_lds(
        (const __attribute__((address_space(1))) unsigned int*)(uintptr_t)g,
        (__attribute__((address_space(3))) unsigned int*)(uintptr_t)l,
        16, 0, 0);
}

// ---- prep: [0,8192) X->Xb bf16 | [8192,16384) W->Wt^T bf16 ----
__global__ __launch_bounds__(256) void prep_kernel(
    const float* __restrict__ X, const float* __restrict__ W,
    unsigned short* __restrict__ Xb, unsigned short* __restrict__ Wt) {
    __shared__ float tile[32][33];
    int blk = blockIdx.x;
    int tid = threadIdx.x;
    if (blk < 8192) {
        int i = blk * 256 + tid;
        float4 v = ((const float4*)X)[i];
        ushort4 o;
        o.x = f2bf(v.x); o.y = f2bf(v.y); o.z = f2bf(v.z); o.w = f2bf(v.w);
        ((ushort4*)Xb)[i] = o;
    } else {
        int t  = blk - 8192;
        int e  = t >> 10;
        int k0 = ((t >> 5) & 31) * 32;
        int n0 = (t & 31) * 32;
        const float* Wp = W + (size_t)e * DIN * DOUT;
        unsigned short* Wtp = Wt + (size_t)e * DIN * DOUT;
        {
            int k  = tid >> 3;
            int c4 = tid & 7;
            float4 v = *(const float4*)(Wp + (size_t)(k0 + k) * DOUT + n0 + c4 * 4);
            tile[k][c4 * 4 + 0] = v.x; tile[k][c4 * 4 + 1] = v.y;
            tile[k][c4 * 4 + 2] = v.z; tile[k][c4 * 4 + 3] = v.w;
        }
        __syncthreads();
        {
            int n  = tid >> 3;
            int kc = tid & 7;
            ushort4 o;
            o.x = f2bf(tile[kc * 4 + 0][n]);
            o.y = f2bf(tile[kc * 4 + 1][n]);
            o.z = f2bf(tile[kc * 4 + 2][n]);
            o.w = f2bf(tile[kc * 4 + 3][n]);
            *(ushort4*)(Wtp + (size_t)(n0 + n) * DIN + k0 + kc * 4) = o;
        }
    }
}

// ---- GEMM: h = relu(Xb_e * Wt_e^T + b_e) -> Hb (bf16) + per-chunk stats P ----
// 128x128x32 tile, 4 waves, 4x4 mfma_f32_16x16x32_bf16. e = blk&7 (XCD affinity).
// P[row][chunk] = (sum, sumsq) over a 64-col chunk; chunk = ni*2 + (wave&1).
__global__ __launch_bounds__(256, 2) void gemm4_kernel(
    const unsigned short* __restrict__ Xb,   // [T][K] bf16
    const unsigned short* __restrict__ Wt,   // [E][N][K] bf16
    const float* __restrict__ Bias,
    unsigned short* __restrict__ Hb,         // [T][DOUT] bf16
    float2* __restrict__ P)                  // [T][16] (sum,sumsq)
{
    __shared__ unsigned short As[BM * BK];
    __shared__ unsigned short Bs[BN * BK];

    int blk = blockIdx.x;                    // 0..511
    int e   = blk & 7;
    int mi  = blk >> 6;
    int m0  = mi * BM;
    int ni  = (blk >> 3) & 7;
    int n0  = ni * BN;

    int tid  = threadIdx.x;
    int wave = tid >> 6;
    int lane = tid & 63;
    int wm   = (wave >> 1) * 64;
    int wn   = (wave & 1) * 64;
    int lrow = lane & 15;
    int quad = lane >> 4;

    const unsigned short* Ag = Xb + (size_t)(e * CAP + m0) * DIN;
    const unsigned short* Bg = Wt + (size_t)e * DOUT * DIN + (size_t)n0 * DIN;

    int l0 = tid;
    int l1 = tid + 256;
    int ar0 = l0 >> 2, ac0 = (l0 & 3) * 8;
    int ar1 = l1 >> 2, ac1 = (l1 & 3) * 8;

    f32x4 acc[4][4];
#pragma unroll
    for (int i = 0; i < 4; i++)
#pragma unroll
        for (int j = 0; j < 4; j++)
            acc[i][j] = (f32x4)(0.0f);

    for (int k0 = 0; k0 < DIN; k0 += BK) {
        gld16(&As[l0 * 8], Ag + (size_t)ar0 * DIN + k0 + ac0);
        gld16(&As[l1 * 8], Ag + (size_t)ar1 * DIN + k0 + ac1);
        gld16(&Bs[l0 * 8], Bg + (size_t)ar0 * DIN + k0 + ac0);
        gld16(&Bs[l1 * 8], Bg + (size_t)ar1 * DIN + k0 + ac1);
        __syncthreads();

        short8 af[4], bf[4];
#pragma unroll
        for (int i = 0; i < 4; i++)
            af[i] = *(const short8*)&As[(wm + i * 16 + lrow) * BK + quad * 8];
#pragma unroll
        for (int j = 0; j < 4; j++)
            bf[j] = *(const short8*)&Bs[(wn + j * 16 + lrow) * BK + quad * 8];
#pragma unroll
        for (int i = 0; i < 4; i++)
#pragma unroll
            for (int j = 0; j < 4; j++)
                acc[i][j] = __builtin_amdgcn_mfma_f32_16x16x32_bf16(af[i], bf[j], acc[i][j], 0, 0, 0);
        __syncthreads();
    }

    float bias[4];
#pragma unroll
    for (int j = 0; j < 4; j++)
        bias[j] = Bias[e * DOUT + n0 + wn + j * 16 + lrow];

    int tok0  = e * CAP + m0 + wm;
    int chunk = ni * 2 + (wave & 1);

#pragma unroll
    for (int i = 0; i < 4; i++) {
#pragma unroll
        for (int r = 0; r < 4; r++) {
            float s = 0.f, ss = 0.f;
#pragma unroll
            for (int j = 0; j < 4; j++) {
                float v = fmaxf(acc[i][j][r] + bias[j], 0.f);
                acc[i][j][r] = v;
                s += v;
                ss = fmaf(v, v, ss);
            }
#pragma unroll
            for (int m = 1; m <= 8; m <<= 1) {   // reduce over lrow (16 lanes)
                s  += __shfl_xor(s, m);
                ss += __shfl_xor(ss, m);
            }
            int grow = tok0 + i * 16 + quad * 4 + r;
            if (lrow == 0)
                P[(size_t)grow * 16 + chunk] = make_float2(s, ss);
#pragma unroll
            for (int j = 0; j < 4; j++) {
                int gcol = n0 + wn + j * 16 + lrow;
                Hb[(size_t)grow * DOUT + gcol] = f2bf(acc[i][j][r]);
            }
        }
    }
}

// ---- LN: read P + bf16 H, write fp32 out ----
__global__ __launch_bounds__(256) void ln2_kernel(
    const unsigned short* __restrict__ Hb,
    const float2* __restrict__ P,
    const float* __restrict__ G,
    const float* __restrict__ Bt,
    float* __restrict__ Out)
{
    int row = blockIdx.x;            // 0..8191
    int e   = row >> 10;
    int tid = threadIdx.x;
    __shared__ float sh[2];

    if (tid < 16) {
        float2 p = P[(size_t)row * 16 + tid];
        float s = p.x, ss = p.y;
#pragma unroll
        for (int m = 1; m <= 8; m <<= 1) {
            s  += __shfl_xor(s, m);
            ss += __shfl_xor(ss, m);
        }
        if (tid == 0) {
            float mu  = s * (1.0f / DOUT);
            float var = fmaxf(ss * (1.0f / DOUT) - mu * mu, 0.f);
            sh[0] = mu;
            sh[1] = rsqrtf(var + LN_EPS);
        }
    }
    __syncthreads();
    float mu = sh[0], rs = sh[1];

    ushort4 hb = ((const ushort4*)Hb)[(size_t)row * 256 + tid];
    float4 g = ((const float4*)G)[e * 256 + tid];
    float4 b = ((const float4*)Bt)[e * 256 + tid];
    float4 y;
    y.x = (bf2f(hb.x) - mu) * rs * g.x + b.x;
    y.y = (bf2f(hb.y) - mu) * rs * g.y + b.y;
    y.z = (bf2f(hb.z) - mu) * rs * g.z + b.z;
    y.w = (bf2f(hb.w) - mu) * rs * g.w + b.w;
    ((float4*)Out)[(size_t)row * 256 + tid] = y;
}

// ================= fallback path (ws too small): R2 kernels =================
__global__ __launch_bounds__(256) void wt_only_kernel(const float* __restrict__ W,
                                                      unsigned short* __restrict__ Wt) {
    __shared__ float tile[32][33];
    int t  = blockIdx.x;
    int e  = t >> 10;
    int k0 = ((t >> 5) & 31) * 32;
    int n0 = (t & 31) * 32;
    int tid = threadIdx.x;
    const float* Wp = W + (size_t)e * DIN * DOUT;
    unsigned short* Wtp = Wt + (size_t)e * DIN * DOUT;
    {
        int k  = tid >> 3;
        int c4 = tid & 7;
        float4 v = *(const float4*)(Wp + (size_t)(k0 + k) * DOUT + n0 + c4 * 4);
        tile[k][c4 * 4 + 0] = v.x; tile[k][c4 * 4 + 1] = v.y;
        tile[k][c4 * 4 + 2] = v.z; tile[k][c4 * 4 + 3] = v.w;
    }
    __syncthreads();
    {
        int n  = tid >> 3;
        int kc = tid & 7;
        ushort4 o;
        o.x = f2bf(tile[kc * 4 + 0][n]);
        o.y = f2bf(tile[kc * 4 + 1][n]);
        o.z = f2bf(tile[kc * 4 + 2][n]);
        o.w = f2bf(tile[kc * 4 + 3][n]);
        *(ushort4*)(Wtp + (size_t)(n0 + n) * DIN + k0 + kc * 4) = o;
    }
}

__global__ __launch_bounds__(256, 2) void gemm_fb_kernel(
    const float* __restrict__ X, const unsigned short* __restrict__ Wt,
    const float* __restrict__ Bias, float* __restrict__ H)
{
    __shared__ unsigned short As[BM * LDSS];
    __shared__ unsigned short Bs[BN * LDSS];
    int blk = blockIdx.x;
    int e   = blk >> 6;
    int tt  = blk & 63;
    int m0  = (tt >> 3) * BM;
    int n0  = (tt & 7) * BN;
    int tid  = threadIdx.x;
    int wave = tid >> 6;
    int lane = tid & 63;
    int wm   = (wave >> 1) * 64;
    int wn   = (wave & 1) * 64;
    int lrow = lane & 15;
    int quad = lane >> 4;
    const float* Xe = X + (size_t)(e * CAP + m0) * DIN;
    const unsigned short* We = Wt + (size_t)e * DOUT * DIN + (size_t)n0 * DIN;
    f32x4 acc[4][4];
#pragma unroll
    for (int i = 0; i < 4; i++)
#pragma unroll
        for (int j = 0; j < 4; j++)
            acc[i][j] = (f32x4)(0.0f);
    for (int k0 = 0; k0 < DIN; k0 += BK) {
#pragma unroll
        for (int i = 0; i < 4; i++) {
            int idx = tid + i * 256;
            int row = idx >> 3;
            int c4  = idx & 7;
            const float4 xv = *(const float4*)(Xe + (size_t)row * DIN + k0 + c4 * 4);
            ushort4 bv;
            bv.x = f2bf(xv.x); bv.y = f2bf(xv.y); bv.z = f2bf(xv.z); bv.w = f2bf(xv.w);
            *(ushort4*)&As[row * LDSS + c4 * 4] = bv;
        }
#pragma unroll
        for (int i = 0; i < 2; i++) {
            int idx = tid + i * 256;
            int row = idx >> 2;
            int c   = idx & 3;
            uint4 wv = *(const uint4*)(We + (size_t)row * DIN + k0 + c * 8);
            *(uint4*)&Bs[row * LDSS + c * 8] = wv;
        }
        __syncthreads();
        short8 af[4], bf[4];
#pragma unroll
        for (int i = 0; i < 4; i++)
            af[i] = *(const short8*)&As[(wm + i * 16 + lrow) * LDSS + quad * 8];
#pragma unroll
        for (int j = 0; j < 4; j++)
            bf[j] = *(const short8*)&Bs[(wn + j * 16 + lrow) * LDSS + quad * 8];
#pragma unroll
        for (int i = 0; i < 4; i++)
#pragma unroll
            for (int j = 0; j < 4; j++)
                acc[i][j] = __builtin_amdgcn_mfma_f32_16x16x32_bf16(af[i], bf[j], acc[i][j], 0, 0, 0);
        __syncthreads();
    }
    float bias[4];
#pragma unroll
    for (int j = 0; j < 4; j++)
        bias[j] = Bias[e * DOUT + n0 + wn + j * 16 + lrow];
    int tok0 = e * CAP + m0 + wm;
#pragma unroll
    for (int i = 0; i < 4; i++)
#pragma unroll
        for (int j = 0; j < 4; j++) {
            int col = n0 + wn + j * 16 + lrow;
#pragma unroll
            for (int r = 0; r < 4; r++) {
                int row = tok0 + i * 16 + quad * 4 + r;
                float v = acc[i][j][r] + bias[j];
                H[(size_t)row * DOUT + col] = fmaxf(v, 0.0f);
            }
        }
}

__global__ __launch_bounds__(256) void ln_kernel(float* __restrict__ H,
                                                 const float* __restrict__ G,
                                                 const float* __restrict__ Bt) {
    int row = blockIdx.x;
    int e   = row >> 10;
    int tid  = threadIdx.x;
    int wave = tid >> 6;
    int lane = tid & 63;
    float* hp = H + (size_t)row * DOUT;
    float4 x = *(const float4*)(hp + tid * 4);
    float s  = x.x + x.y + x.z + x.w;
    float ss = fmaf(x.x, x.x, fmaf(x.y, x.y, fmaf(x.z, x.z, x.w * x.w)));
#pragma unroll
    for (int m = 32; m >= 1; m >>= 1) {
        s  += __shfl_xor(s, m);
        ss += __shfl_xor(ss, m);
    }
    __shared__ float red[8];
    if (lane == 0) { red[wave] = s; red[4 + wave] = ss; }
    __syncthreads();
    float ts  = red[0] + red[1] + red[2] + red[3];
    float tss = red[4] + red[5] + red[6] + red[7];
    float mean = ts * (1.0f / DOUT);
    float var  = fmaxf(tss * (1.0f / DOUT) - mean * mean, 0.0f);
    float rs = rsqrtf(var + LN_EPS);
    float4 g = *(const float4*)(G  + (size_t)e * DOUT + tid * 4);
    float4 b = *(const float4*)(Bt + (size_t)e * DOUT + tid * 4);
    float4 y;
    y.x = (x.x - mean) * rs * g.x + b.x;
    y.y = (x.y - mean) * rs * g.y + b.y;
    y.z = (x.z - mean) * rs * g.z + b.z;
    y.w = (x.w - mean) * rs * g.w + b.w;
    *(float4*)(hp + tid * 4) = y;
}

extern "C" void kernel_launch(void* const* d_in, const int* in_sizes, int n_in,
                              void* d_out, int out_size, void* d_ws, size_t ws_size,
                              hipStream_t stream) {
    const float* x  = (const float*)d_in[0];
    const float* W  = (const float*)d_in[2];
    const float* b  = (const float*)d_in[3];
    const float* g  = (const float*)d_in[4];
    const float* be = (const float*)d_in[5];
    float* out = (float*)d_out;

    const size_t WT_BYTES = (size_t)NEXP * DIN * DOUT * 2;   // 16 MB
    const size_t XB_BYTES = (size_t)T_TOK * DIN * 2;         // 16 MB
    const size_t HB_BYTES = (size_t)T_TOK * DOUT * 2;        // 16 MB
    const size_t P_BYTES  = (size_t)T_TOK * 16 * 8;          // 1 MB
    const size_t NEEDED   = WT_BYTES + XB_BYTES + HB_BYTES + P_BYTES;

    unsigned short* Wt = (unsigned short*)d_ws;
    dim3 tb(256);

    if (ws_size >= NEEDED) {
        unsigned short* Xb = (unsigned short*)((char*)d_ws + WT_BYTES);
        unsigned short* Hb = (unsigned short*)((char*)d_ws + WT_BYTES + XB_BYTES);
        float2* P = (float2*)((char*)d_ws + WT_BYTES + XB_BYTES + HB_BYTES);
        prep_kernel<<<dim3(16384), tb, 0, stream>>>(x, W, Xb, Wt);
        gemm4_kernel<<<dim3(512), tb, 0, stream>>>(Xb, Wt, b, Hb, P);
        ln2_kernel<<<dim3(8192), tb, 0, stream>>>(Hb, P, g, be, out);
    } else {
        wt_only_kernel<<<dim3(8192), tb, 0, stream>>>(W, Wt);
        gemm_fb_kernel<<<dim3(512), tb, 0, stream>>>(x, Wt, b, out);
        ln_kernel<<<dim3(8192), tb, 0, stream>>>(out, g, be);
    }
}